// Round 2
// baseline (1827.328 us; speedup 1.0000x reference)
//
#include <hip/hip_runtime.h>
#include <math.h>

#define BB 16
#define HH 512
#define WW 512
#define HWP (HH*WW)
#define NPIX (BB*HWP)
#define NCORN 500
#define CAND_CAP 6144

__device__ __constant__ float G7c[7] = {
    0.0044330482f, 0.0540055826f, 0.2420362294f, 0.3990502793f,
    0.2420362294f, 0.0540055826f, 0.0044330482f};

__device__ __forceinline__ int reflect_idx(int i, int n) {
    if (i < 0) i = -i;
    if (i >= n) i = 2 * n - 2 - i;
    return i;
}

// 1) gray = 0.299 R + 0.587 G + 0.114 B
__global__ void k_gray(const float* __restrict__ imgs, float* __restrict__ gray) {
    int i = blockIdx.x * blockDim.x + threadIdx.x;
    if (i >= NPIX) return;
    int b = i / HWP, p = i % HWP;
    const float* base = imgs + (size_t)b * 3 * HWP;
    gray[i] = 0.299f * base[p] + 0.587f * base[p + HWP] + 0.114f * base[p + 2 * HWP];
}

// 2) sobel grads (replicate pad), structure tensor products
__global__ void k_grad(const float* __restrict__ gray,
                       float* __restrict__ dx2, float* __restrict__ dy2,
                       float* __restrict__ dxy) {
    int i = blockIdx.x * blockDim.x + threadIdx.x;
    if (i >= NPIX) return;
    int b = i / HWP, p = i % HWP, y = p / WW, x = p % WW;
    const float* g = gray + (size_t)b * HWP;
    int ym = max(y - 1, 0), yp = min(y + 1, HH - 1);
    int xm = max(x - 1, 0), xp = min(x + 1, WW - 1);
    float g00 = g[ym * WW + xm], g01 = g[ym * WW + x], g02 = g[ym * WW + xp];
    float g10 = g[y * WW + xm],                         g12 = g[y * WW + xp];
    float g20 = g[yp * WW + xm], g21 = g[yp * WW + x], g22 = g[yp * WW + xp];
    float dx = (g02 - g00 + 2.f * (g12 - g10) + g22 - g20) * 0.125f;
    float dy = (g20 - g00 + 2.f * (g21 - g01) + g22 - g02) * 0.125f;
    dx2[i] = dx * dx;
    dy2[i] = dy * dy;
    dxy[i] = dx * dy;
}

// 3) 7x7 gaussian blur (reflect) of the 3 channels + min-eigenvalue
__global__ void k_gftt(const float* __restrict__ dx2, const float* __restrict__ dy2,
                       const float* __restrict__ dxy, float* __restrict__ S) {
    int i = blockIdx.x * blockDim.x + threadIdx.x;
    if (i >= NPIX) return;
    int b = i / HWP, p = i % HWP, y = p / WW, x = p % WW;
    size_t base = (size_t)b * HWP;
    float a = 0.f, c = 0.f, d = 0.f;
    for (int j = -3; j <= 3; ++j) {
        int yy = reflect_idx(y + j, HH);
        float gj = G7c[j + 3];
        const float* r0 = dx2 + base + (size_t)yy * WW;
        const float* r1 = dy2 + base + (size_t)yy * WW;
        const float* r2 = dxy + base + (size_t)yy * WW;
        for (int ii = -3; ii <= 3; ++ii) {
            int xx = reflect_idx(x + ii, WW);
            float w = gj * G7c[ii + 3];
            a += w * r0[xx];
            c += w * r1[xx];
            d += w * r2[xx];
        }
    }
    float det = a * c - d * d;
    float tr = a + c;
    S[i] = 0.5f * (tr - sqrtf(fabsf(tr * tr - 4.f * det)));
}

// 4) 5x5 NMS: keep value iff equal to in-bounds window max
__global__ void k_nms1(const float* __restrict__ S, float* __restrict__ C) {
    int i = blockIdx.x * blockDim.x + threadIdx.x;
    if (i >= NPIX) return;
    int b = i / HWP, p = i % HWP, y = p / WW, x = p % WW;
    const float* sb = S + (size_t)b * HWP;
    float v = sb[p];
    float m = -INFINITY;
    int y0 = max(y - 2, 0), y1 = min(y + 2, HH - 1);
    int x0 = max(x - 2, 0), x1 = min(x + 2, WW - 1);
    for (int yy = y0; yy <= y1; ++yy)
        for (int xx = x0; xx <= x1; ++xx)
            m = fmaxf(m, sb[yy * WW + xx]);
    C[i] = (v == m) ? v : 0.f;
}

// 5) per 8x8 block max (one wave per block); push positive maxima as candidates
__global__ void k_cand(const float* __restrict__ C, float* __restrict__ cand_val,
                       int* __restrict__ cand_idx, int* __restrict__ cnt) {
    int bx = blockIdx.x, by = blockIdx.y, b = blockIdx.z;
    int lane = threadIdx.x;
    int ly = lane >> 3, lx = lane & 7;
    int y = by * 8 + ly, x = bx * 8 + lx;
    float v = C[(size_t)b * HWP + y * WW + x];
    float m = v;
    for (int off = 32; off; off >>= 1)
        m = fmaxf(m, __shfl_xor(m, off));
    if (v == m && v > 0.f) {
        int pos = atomicAdd(&cnt[b], 1);
        if (pos < CAND_CAP) {
            cand_val[b * CAND_CAP + pos] = v;
            cand_idx[b * CAND_CAP + pos] = y * WW + x;
        }
    }
}

// 6) exact top-500 per batch via O(n^2) rank with composite key; scatter into target
__global__ void k_select(const float* __restrict__ cand_val, const int* __restrict__ cand_idx,
                         const int* __restrict__ cnt, float* __restrict__ target) {
    __shared__ unsigned long long keys[CAND_CAP];
    int b = blockIdx.x;
    int n = cnt[b];
    if (n > CAND_CAP) n = CAND_CAP;
    for (int i = threadIdx.x; i < n; i += blockDim.x) {
        unsigned int vb = __float_as_uint(cand_val[b * CAND_CAP + i]);
        unsigned int ix = (unsigned int)cand_idx[b * CAND_CAP + i];
        keys[i] = ((unsigned long long)vb << 32) | (unsigned int)(~ix);
    }
    __syncthreads();
    for (int i = threadIdx.x; i < n; i += blockDim.x) {
        unsigned long long k = keys[i];
        int rank = 0;
        for (int j = 0; j < n; ++j) rank += (keys[j] > k) ? 1 : 0;
        if (rank < NCORN) {
            unsigned int ix = ~(unsigned int)(k & 0xffffffffull);
            float v = __uint_as_float((unsigned int)(k >> 32));
            target[(size_t)b * HWP + ix] = v;
        }
    }
}

// 7) second 5x5 NMS on sparse target, output binary mask
__global__ void k_nms2(const float* __restrict__ target, float* __restrict__ M) {
    int i = blockIdx.x * blockDim.x + threadIdx.x;
    if (i >= NPIX) return;
    int b = i / HWP, p = i % HWP, y = p / WW, x = p % WW;
    const float* tb = target + (size_t)b * HWP;
    float t = tb[p];
    float out = 0.f;
    if (t > 0.f) {
        float m = -INFINITY;
        int y0 = max(y - 2, 0), y1 = min(y + 2, HH - 1);
        int x0 = max(x - 2, 0), x1 = min(x + 2, WW - 1);
        for (int yy = y0; yy <= y1; ++yy)
            for (int xx = x0; xx <= x1; ++xx)
                m = fmaxf(m, tb[yy * WW + xx]);
        out = (t == m) ? 1.f : 0.f;
    }
    M[i] = out;
}

// 8) 7x7 gaussian blur (reflect) of binary mask -> corners
__global__ void k_blur7(const float* __restrict__ M, float* __restrict__ corners) {
    int i = blockIdx.x * blockDim.x + threadIdx.x;
    if (i >= NPIX) return;
    int b = i / HWP, p = i % HWP, y = p / WW, x = p % WW;
    size_t base = (size_t)b * HWP;
    float acc = 0.f;
    for (int j = -3; j <= 3; ++j) {
        int yy = reflect_idx(y + j, HH);
        float gj = G7c[j + 3];
        const float* r = M + base + (size_t)yy * WW;
        for (int ii = -3; ii <= 3; ++ii) {
            int xx = reflect_idx(x + ii, WW);
            acc += gj * G7c[ii + 3] * r[xx];
        }
    }
    corners[i] = acc;
}

// 9) fused BCE + laplacian regularizer, block-reduced into accumulators
__global__ void k_loss(const float* __restrict__ scores, const float* __restrict__ corners,
                       float* __restrict__ accum) {
    int i = blockIdx.x * blockDim.x + threadIdx.x;
    float bce = 0.f, reg = 0.f;
    if (i < NPIX) {
        float p = scores[i];
        float c = corners[i];
        float lp = logf(p);
        lp = (lp > -100.f) ? lp : -100.f;
        float l1p = log1pf(-p);
        l1p = (l1p > -100.f) ? l1p : -100.f;
        bce = -(c * lp + (1.f - c) * l1p);
        int b = i / HWP, pix = i % HWP, y = pix / WW, x = pix % WW;
        const float* sb = scores + (size_t)b * HWP;
        float s25 = 0.f;
        for (int j = -2; j <= 2; ++j) {
            int yy = reflect_idx(y + j, HH);
            const float* r = sb + (size_t)yy * WW;
            for (int ii = -2; ii <= 2; ++ii) {
                int xx = reflect_idx(x + ii, WW);
                s25 += r[xx];
            }
        }
        float lap = (s25 - 25.f * p) * (1.0f / 48.0f);
        reg = p * expf(-lap);
    }
    for (int off = 32; off; off >>= 1) {
        bce += __shfl_down(bce, off);
        reg += __shfl_down(reg, off);
    }
    __shared__ float wb[4], wr[4];
    int wid = threadIdx.x >> 6, lid = threadIdx.x & 63;
    if (lid == 0) { wb[wid] = bce; wr[wid] = reg; }
    __syncthreads();
    if (threadIdx.x == 0) {
        float tb = 0.f, tr = 0.f;
        for (int w = 0; w < 4; ++w) { tb += wb[w]; tr += wr[w]; }
        atomicAdd(&accum[0], tb);
        atomicAdd(&accum[1], tr);
    }
}

// 10) finalize scalar
__global__ void k_final(const float* __restrict__ accum, float* __restrict__ out) {
    if (threadIdx.x == 0 && blockIdx.x == 0) {
        float invN = 1.0f / (float)NPIX;
        out[0] = accum[0] * invN + accum[1] * invN * 10.0f;
    }
}

extern "C" void kernel_launch(void* const* d_in, const int* in_sizes, int n_in,
                              void* d_out, int out_size, void* d_ws, size_t ws_size,
                              hipStream_t stream) {
    const float* scores = (const float*)d_in[0];
    const float* imgs   = (const float*)d_in[1];
    float* out = (float*)d_out;

    float* ws = (float*)d_ws;
    float* A0 = ws;                 // gray -> S
    float* A1 = ws + (size_t)NPIX;  // dx2 -> C -> M
    float* A2 = ws + 2 * (size_t)NPIX;  // dy2 -> corners
    float* A3 = ws + 3 * (size_t)NPIX;  // dxy -> target
    float* cand_val = ws + 4 * (size_t)NPIX;
    int*   cand_idx = (int*)(cand_val + BB * CAND_CAP);
    int*   cnt      = (int*)(cand_val + 2 * (size_t)BB * CAND_CAP);
    float* accum    = (float*)(cnt + BB);

    const int T = 256;
    const int GB = (NPIX + T - 1) / T;

    k_gray<<<GB, T, 0, stream>>>(imgs, A0);
    k_grad<<<GB, T, 0, stream>>>(A0, A1, A2, A3);
    k_gftt<<<GB, T, 0, stream>>>(A1, A2, A3, A0);
    k_nms1<<<GB, T, 0, stream>>>(A0, A1);

    // zero target (A3 free after k_gftt), counters and accumulators
    hipMemsetAsync(A3, 0, (size_t)NPIX * sizeof(float), stream);
    hipMemsetAsync(cnt, 0, BB * sizeof(int) + 2 * sizeof(float), stream);

    dim3 gcand(WW / 8, HH / 8, BB);
    k_cand<<<gcand, 64, 0, stream>>>(A1, cand_val, cand_idx, cnt);
    k_select<<<BB, 512, 0, stream>>>(cand_val, cand_idx, cnt, A3);
    k_nms2<<<GB, T, 0, stream>>>(A3, A1);
    k_blur7<<<GB, T, 0, stream>>>(A1, A2);
    k_loss<<<GB, T, 0, stream>>>(scores, A2, accum);
    k_final<<<1, 64, 0, stream>>>(accum, out);
}

// Round 3
// 734.196 us; speedup vs baseline: 2.4889x; 2.4889x over previous
//
#include <hip/hip_runtime.h>
#include <math.h>

#define BB 16
#define HH 512
#define WW 512
#define HWP (HH*WW)
#define NPIX (BB*HWP)
#define NCORN 500
#define NSLOT 4096      // 64x64 tiles of 8x8 per image
#define OCAP 1024       // overflow for exact ties with block max (rare)
#define NKEY (NSLOT+OCAP)

__device__ __constant__ float G7c[7] = {
    0.0044330482f, 0.0540055826f, 0.2420362294f, 0.3990502793f,
    0.2420362294f, 0.0540055826f, 0.0044330482f};

__device__ __forceinline__ int reflect_idx(int i, int n) {
    if (i < 0) i = -i;
    if (i >= n) i = 2 * n - 2 - i;
    return i;
}

// 1) gray = 0.299 R + 0.587 G + 0.114 B
__global__ void k_gray(const float* __restrict__ imgs, float* __restrict__ gray) {
    int i = blockIdx.x * blockDim.x + threadIdx.x;
    if (i >= NPIX) return;
    int b = i / HWP, p = i % HWP;
    const float* base = imgs + (size_t)b * 3 * HWP;
    gray[i] = 0.299f * base[p] + 0.587f * base[p + HWP] + 0.114f * base[p + 2 * HWP];
}

// 2) fused sobel (replicate) + horizontal 7-tap gaussian (reflect) of products
__global__ void k_gradH(const float* __restrict__ gray,
                        float* __restrict__ ha, float* __restrict__ hc,
                        float* __restrict__ hd) {
    int i = blockIdx.x * blockDim.x + threadIdx.x;
    if (i >= NPIX) return;
    int b = i / HWP, p = i % HWP, y = p / WW, x = p % WW;
    const float* g = gray + (size_t)b * HWP;
    int ym = max(y - 1, 0) * WW, yc = y * WW, yp = min(y + 1, HH - 1) * WW;
    float a = 0.f, c = 0.f, d = 0.f;
#pragma unroll
    for (int t = -3; t <= 3; ++t) {
        int xx = reflect_idx(x + t, WW);
        int xm = max(xx - 1, 0), xp = min(xx + 1, WW - 1);
        float g00 = g[ym + xm], g01 = g[ym + xx], g02 = g[ym + xp];
        float g10 = g[yc + xm],                   g12 = g[yc + xp];
        float g20 = g[yp + xm], g21 = g[yp + xx], g22 = g[yp + xp];
        float dx = (g02 - g00 + 2.f * (g12 - g10) + g22 - g20) * 0.125f;
        float dy = (g20 - g00 + 2.f * (g21 - g01) + g22 - g02) * 0.125f;
        float w = G7c[t + 3];
        a += w * dx * dx;
        c += w * dy * dy;
        d += w * dx * dy;
    }
    ha[i] = a; hc[i] = c; hd[i] = d;
}

// 3) vertical 7-tap gaussian (reflect) + min-eigenvalue
__global__ void k_gfttV(const float* __restrict__ ha, const float* __restrict__ hc,
                        const float* __restrict__ hd, float* __restrict__ S) {
    int i = blockIdx.x * blockDim.x + threadIdx.x;
    if (i >= NPIX) return;
    int b = i / HWP, p = i % HWP, y = p / WW, x = p % WW;
    size_t base = (size_t)b * HWP;
    float a = 0.f, c = 0.f, d = 0.f;
#pragma unroll
    for (int j = -3; j <= 3; ++j) {
        int yy = reflect_idx(y + j, HH);
        float w = G7c[j + 3];
        size_t o = base + (size_t)yy * WW + x;
        a += w * ha[o];
        c += w * hc[o];
        d += w * hd[o];
    }
    float det = a * c - d * d;
    float tr = a + c;
    S[i] = 0.5f * (tr - sqrtf(fabsf(tr * tr - 4.f * det)));
}

// 4a) horizontal 5-wide max (in-bounds)
__global__ void k_nms1h(const float* __restrict__ S, float* __restrict__ hm) {
    int i = blockIdx.x * blockDim.x + threadIdx.x;
    if (i >= NPIX) return;
    int p = i % HWP, x = p % WW;
    const float* row = S + (i - x);
    int x0 = max(x - 2, 0), x1 = min(x + 2, WW - 1);
    float m = -INFINITY;
    for (int xx = x0; xx <= x1; ++xx) m = fmaxf(m, row[xx]);
    hm[i] = m;
}

// 4b) vertical 5-wide max of hm; keep S value iff equal to window max
__global__ void k_nms1v(const float* __restrict__ hm, const float* __restrict__ S,
                        float* __restrict__ C) {
    int i = blockIdx.x * blockDim.x + threadIdx.x;
    if (i >= NPIX) return;
    int b = i / HWP, p = i % HWP, y = p / WW, x = p % WW;
    const float* hb = hm + (size_t)b * HWP;
    int y0 = max(y - 2, 0), y1 = min(y + 2, HH - 1);
    float m = -INFINITY;
    for (int yy = y0; yy <= y1; ++yy) m = fmaxf(m, hb[yy * WW + x]);
    float v = S[i];
    C[i] = (v == m) ? v : 0.f;
}

// 5) per 8x8 tile max -> fixed slot (no contended atomics); ties overflow
__global__ void k_cand(const float* __restrict__ C, float* __restrict__ sval,
                       int* __restrict__ sidx, int* __restrict__ ocnt) {
    int wave = threadIdx.x >> 6, lane = threadIdx.x & 63;
    int tx = blockIdx.x * 4 + wave;      // tile col 0..63
    int ty = blockIdx.y;                 // tile row 0..63
    int b = blockIdx.z;
    int ly = lane >> 3, lx = lane & 7;
    int y = ty * 8 + ly, x = tx * 8 + lx;
    float v = C[(size_t)b * HWP + y * WW + x];
    float m = v;
#pragma unroll
    for (int off = 32; off; off >>= 1)
        m = fmaxf(m, __shfl_xor(m, off));
    unsigned long long mask = __ballot(v == m && v > 0.f);
    int slot = ty * 64 + tx;
    if (mask) {
        int first = __ffsll((unsigned long long)mask) - 1;
        if (lane == first) {
            sval[b * NKEY + slot] = v;
            sidx[b * NKEY + slot] = y * WW + x;
        } else if ((mask >> lane) & 1ull) {
            int pos = atomicAdd(&ocnt[b], 1);
            if (pos < OCAP) {
                sval[b * NKEY + NSLOT + pos] = v;
                sidx[b * NKEY + NSLOT + pos] = y * WW + x;
            }
        }
    } else if (lane == 0) {
        sval[b * NKEY + slot] = 0.f;
        sidx[b * NKEY + slot] = 0;
    }
}

// 6) exact top-500 per image; chunked rank over LDS-cached keys; scatter
__global__ void k_select(const float* __restrict__ sval, const int* __restrict__ sidx,
                         const int* __restrict__ ocnt, float* __restrict__ target) {
    __shared__ unsigned long long keys[NKEY];
    int b = blockIdx.x;
    int n = NSLOT + min(ocnt[b], OCAP);
    for (int i = threadIdx.x; i < n; i += blockDim.x) {
        float v = sval[b * NKEY + i];
        unsigned long long k = 0ull;
        if (v > 0.f) {
            unsigned int ix = (unsigned int)sidx[b * NKEY + i];
            k = ((unsigned long long)__float_as_uint(v) << 32) | (unsigned int)(~ix);
        }
        keys[i] = k;
    }
    __syncthreads();
    int i0 = blockIdx.y * blockDim.x + threadIdx.x;
    if (i0 >= n) return;
    unsigned long long k = keys[i0];
    if (k == 0ull) return;
    int rank = 0;
    for (int j = 0; j < n; ++j) rank += (keys[j] > k) ? 1 : 0;
    if (rank < NCORN) {
        unsigned int ix = ~(unsigned int)(k & 0xffffffffull);
        float v = __uint_as_float((unsigned int)(k >> 32));
        target[(size_t)b * HWP + ix] = v;
    }
}

// 7) second 5x5 NMS on sparse target, output binary mask
__global__ void k_nms2(const float* __restrict__ target, float* __restrict__ M) {
    int i = blockIdx.x * blockDim.x + threadIdx.x;
    if (i >= NPIX) return;
    int b = i / HWP, p = i % HWP, y = p / WW, x = p % WW;
    const float* tb = target + (size_t)b * HWP;
    float t = tb[p];
    float out = 0.f;
    if (t > 0.f) {
        float m = -INFINITY;
        int y0 = max(y - 2, 0), y1 = min(y + 2, HH - 1);
        int x0 = max(x - 2, 0), x1 = min(x + 2, WW - 1);
        for (int yy = y0; yy <= y1; ++yy)
            for (int xx = x0; xx <= x1; ++xx)
                m = fmaxf(m, tb[yy * WW + xx]);
        out = (t == m) ? 1.f : 0.f;
    }
    M[i] = out;
}

// 8a) horizontal 7-tap gaussian (reflect)
__global__ void k_blur7h(const float* __restrict__ M, float* __restrict__ T) {
    int i = blockIdx.x * blockDim.x + threadIdx.x;
    if (i >= NPIX) return;
    int p = i % HWP, x = p % WW;
    const float* row = M + (i - x);
    float acc = 0.f;
#pragma unroll
    for (int t = -3; t <= 3; ++t)
        acc += G7c[t + 3] * row[reflect_idx(x + t, WW)];
    T[i] = acc;
}

// 8b) vertical 7-tap gaussian (reflect)
__global__ void k_blur7v(const float* __restrict__ T, float* __restrict__ corners) {
    int i = blockIdx.x * blockDim.x + threadIdx.x;
    if (i >= NPIX) return;
    int b = i / HWP, p = i % HWP, y = p / WW, x = p % WW;
    const float* cb = T + (size_t)b * HWP;
    float acc = 0.f;
#pragma unroll
    for (int j = -3; j <= 3; ++j)
        acc += G7c[j + 3] * cb[reflect_idx(y + j, HH) * WW + x];
    corners[i] = acc;
}

// 9) fused BCE + laplacian regularizer, block-reduced into accumulators
__global__ void k_loss(const float* __restrict__ scores, const float* __restrict__ corners,
                       float* __restrict__ accum) {
    int i = blockIdx.x * blockDim.x + threadIdx.x;
    float bce = 0.f, reg = 0.f;
    if (i < NPIX) {
        float p = scores[i];
        float c = corners[i];
        float lp = __logf(p);
        lp = (lp > -100.f) ? lp : -100.f;
        float l1p = __logf(1.f - p);
        l1p = (l1p > -100.f) ? l1p : -100.f;
        bce = -(c * lp + (1.f - c) * l1p);
        int b = i / HWP, pix = i % HWP, y = pix / WW, x = pix % WW;
        const float* sb = scores + (size_t)b * HWP;
        float s25 = 0.f;
        for (int j = -2; j <= 2; ++j) {
            int yy = reflect_idx(y + j, HH);
            const float* r = sb + (size_t)yy * WW;
            for (int ii = -2; ii <= 2; ++ii) {
                int xx = reflect_idx(x + ii, WW);
                s25 += r[xx];
            }
        }
        float lap = (s25 - 25.f * p) * (1.0f / 48.0f);
        reg = p * __expf(-lap);
    }
#pragma unroll
    for (int off = 32; off; off >>= 1) {
        bce += __shfl_down(bce, off);
        reg += __shfl_down(reg, off);
    }
    __shared__ float wb[4], wr[4];
    int wid = threadIdx.x >> 6, lid = threadIdx.x & 63;
    if (lid == 0) { wb[wid] = bce; wr[wid] = reg; }
    __syncthreads();
    if (threadIdx.x == 0) {
        float tb = 0.f, tr = 0.f;
        for (int w = 0; w < 4; ++w) { tb += wb[w]; tr += wr[w]; }
        atomicAdd(&accum[0], tb);
        atomicAdd(&accum[1], tr);
    }
}

// 10) finalize scalar
__global__ void k_final(const float* __restrict__ accum, float* __restrict__ out) {
    if (threadIdx.x == 0 && blockIdx.x == 0) {
        float invN = 1.0f / (float)NPIX;
        out[0] = accum[0] * invN + accum[1] * invN * 10.0f;
    }
}

extern "C" void kernel_launch(void* const* d_in, const int* in_sizes, int n_in,
                              void* d_out, int out_size, void* d_ws, size_t ws_size,
                              hipStream_t stream) {
    const float* scores = (const float*)d_in[0];
    const float* imgs   = (const float*)d_in[1];
    float* out = (float*)d_out;

    float* ws = (float*)d_ws;
    float* A0 = ws;                     // gray -> S -> M
    float* A1 = ws + (size_t)NPIX;      // ha -> nms1 rowmax -> blur7 tmp
    float* A2 = ws + 2 * (size_t)NPIX;  // hc -> C -> corners
    float* A3 = ws + 3 * (size_t)NPIX;  // hd -> target
    float* sval = ws + 4 * (size_t)NPIX;          // [BB][NKEY]
    int*   sidx = (int*)(sval + (size_t)BB * NKEY);
    int*   ocnt = (int*)(sidx + (size_t)BB * NKEY);  // [BB] + accum[2] right after
    float* accum = (float*)(ocnt + BB);

    const int T = 256;
    const int GB = (NPIX + T - 1) / T;

    k_gray <<<GB, T, 0, stream>>>(imgs, A0);
    k_gradH<<<GB, T, 0, stream>>>(A0, A1, A2, A3);
    k_gfttV<<<GB, T, 0, stream>>>(A1, A2, A3, A0);
    k_nms1h<<<GB, T, 0, stream>>>(A0, A1);
    k_nms1v<<<GB, T, 0, stream>>>(A1, A0, A2);

    hipMemsetAsync(A3, 0, (size_t)NPIX * sizeof(float), stream);       // target
    hipMemsetAsync(ocnt, 0, BB * sizeof(int) + 2 * sizeof(float), stream);

    dim3 gcand(16, 64, BB);
    k_cand<<<gcand, 256, 0, stream>>>(A2, sval, sidx, ocnt);
    dim3 gsel(BB, (NKEY + 511) / 512);
    k_select<<<gsel, 512, 0, stream>>>(sval, sidx, ocnt, A3);
    k_nms2  <<<GB, T, 0, stream>>>(A3, A0);
    k_blur7h<<<GB, T, 0, stream>>>(A0, A1);
    k_blur7v<<<GB, T, 0, stream>>>(A1, A2);
    k_loss  <<<GB, T, 0, stream>>>(scores, A2, accum);
    k_final <<<1, 64, 0, stream>>>(accum, out);
}

// Round 4
// 335.803 us; speedup vs baseline: 5.4417x; 2.1864x over previous
//
#include <hip/hip_runtime.h>
#include <math.h>

#define BB 16
#define HH 512
#define WW 512
#define HWP (HH*WW)
#define NPIX (BB*HWP)
#define NCORN 500
#define NSLOT 4096      // 64x64 tiles of 8x8 per image
#define OCAP 1024       // overflow for exact ties with block max (rare)
#define NKEY (NSLOT+OCAP)
#define NB_LOSS 2048    // k_loss grid blocks (partial-sum slots)

__device__ __constant__ float G7c[7] = {
    0.0044330482f, 0.0540055826f, 0.2420362294f, 0.3990502793f,
    0.2420362294f, 0.0540055826f, 0.0044330482f};

__device__ __forceinline__ int reflect_idx(int i, int n) {
    if (i < 0) i = -i;
    if (i >= n) i = 2 * n - 2 - i;
    return i;
}

// 1) gray = 0.299 R + 0.587 G + 0.114 B
__global__ void k_gray(const float* __restrict__ imgs, float* __restrict__ gray) {
    int i = blockIdx.x * blockDim.x + threadIdx.x;
    if (i >= NPIX) return;
    int b = i / HWP, p = i % HWP;
    const float* base = imgs + (size_t)b * 3 * HWP;
    gray[i] = 0.299f * base[p] + 0.587f * base[p + HWP] + 0.114f * base[p + 2 * HWP];
}

// 2) fused sobel (replicate) + horizontal 7-tap gaussian (reflect) of products
__global__ void k_gradH(const float* __restrict__ gray,
                        float* __restrict__ ha, float* __restrict__ hc,
                        float* __restrict__ hd) {
    int i = blockIdx.x * blockDim.x + threadIdx.x;
    if (i >= NPIX) return;
    int b = i / HWP, p = i % HWP, y = p / WW, x = p % WW;
    const float* g = gray + (size_t)b * HWP;
    int ym = max(y - 1, 0) * WW, yc = y * WW, yp = min(y + 1, HH - 1) * WW;
    float a = 0.f, c = 0.f, d = 0.f;
#pragma unroll
    for (int t = -3; t <= 3; ++t) {
        int xx = reflect_idx(x + t, WW);
        int xm = max(xx - 1, 0), xp = min(xx + 1, WW - 1);
        float g00 = g[ym + xm], g01 = g[ym + xx], g02 = g[ym + xp];
        float g10 = g[yc + xm],                   g12 = g[yc + xp];
        float g20 = g[yp + xm], g21 = g[yp + xx], g22 = g[yp + xp];
        float dx = (g02 - g00 + 2.f * (g12 - g10) + g22 - g20) * 0.125f;
        float dy = (g20 - g00 + 2.f * (g21 - g01) + g22 - g02) * 0.125f;
        float w = G7c[t + 3];
        a += w * dx * dx;
        c += w * dy * dy;
        d += w * dx * dy;
    }
    ha[i] = a; hc[i] = c; hd[i] = d;
}

// 3) vertical 7-tap gaussian (reflect) + min-eigenvalue
__global__ void k_gfttV(const float* __restrict__ ha, const float* __restrict__ hc,
                        const float* __restrict__ hd, float* __restrict__ S) {
    int i = blockIdx.x * blockDim.x + threadIdx.x;
    if (i >= NPIX) return;
    int b = i / HWP, p = i % HWP, y = p / WW, x = p % WW;
    size_t base = (size_t)b * HWP;
    float a = 0.f, c = 0.f, d = 0.f;
#pragma unroll
    for (int j = -3; j <= 3; ++j) {
        int yy = reflect_idx(y + j, HH);
        float w = G7c[j + 3];
        size_t o = base + (size_t)yy * WW + x;
        a += w * ha[o];
        c += w * hc[o];
        d += w * hd[o];
    }
    float det = a * c - d * d;
    float tr = a + c;
    S[i] = 0.5f * (tr - sqrtf(fabsf(tr * tr - 4.f * det)));
}

// 4a) horizontal 5-wide max (in-bounds)
__global__ void k_nms1h(const float* __restrict__ S, float* __restrict__ hm) {
    int i = blockIdx.x * blockDim.x + threadIdx.x;
    if (i >= NPIX) return;
    int p = i % HWP, x = p % WW;
    const float* row = S + (i - x);
    int x0 = max(x - 2, 0), x1 = min(x + 2, WW - 1);
    float m = -INFINITY;
    for (int xx = x0; xx <= x1; ++xx) m = fmaxf(m, row[xx]);
    hm[i] = m;
}

// 4b) vertical 5-wide max of hm; keep S value iff equal to window max
__global__ void k_nms1v(const float* __restrict__ hm, const float* __restrict__ S,
                        float* __restrict__ C) {
    int i = blockIdx.x * blockDim.x + threadIdx.x;
    if (i >= NPIX) return;
    int b = i / HWP, p = i % HWP, y = p / WW, x = p % WW;
    const float* hb = hm + (size_t)b * HWP;
    int y0 = max(y - 2, 0), y1 = min(y + 2, HH - 1);
    float m = -INFINITY;
    for (int yy = y0; yy <= y1; ++yy) m = fmaxf(m, hb[yy * WW + x]);
    float v = S[i];
    C[i] = (v == m) ? v : 0.f;
}

// 5) per 8x8 tile max -> fixed slot (no contended atomics); ties overflow
__global__ void k_cand(const float* __restrict__ C, float* __restrict__ sval,
                       int* __restrict__ sidx, int* __restrict__ ocnt) {
    int wave = threadIdx.x >> 6, lane = threadIdx.x & 63;
    int tx = blockIdx.x * 4 + wave;      // tile col 0..63
    int ty = blockIdx.y;                 // tile row 0..63
    int b = blockIdx.z;
    int ly = lane >> 3, lx = lane & 7;
    int y = ty * 8 + ly, x = tx * 8 + lx;
    float v = C[(size_t)b * HWP + y * WW + x];
    float m = v;
#pragma unroll
    for (int off = 32; off; off >>= 1)
        m = fmaxf(m, __shfl_xor(m, off));
    unsigned long long mask = __ballot(v == m && v > 0.f);
    int slot = ty * 64 + tx;
    if (mask) {
        int first = __ffsll((unsigned long long)mask) - 1;
        if (lane == first) {
            sval[b * NKEY + slot] = v;
            sidx[b * NKEY + slot] = y * WW + x;
        } else if ((mask >> lane) & 1ull) {
            int pos = atomicAdd(&ocnt[b], 1);
            if (pos < OCAP) {
                sval[b * NKEY + NSLOT + pos] = v;
                sidx[b * NKEY + NSLOT + pos] = y * WW + x;
            }
        }
    } else if (lane == 0) {
        sval[b * NKEY + slot] = 0.f;
        sidx[b * NKEY + slot] = 0;
    }
}

// 6) exact top-500 per image; chunked rank over LDS-cached keys; scatter
__global__ void k_select(const float* __restrict__ sval, const int* __restrict__ sidx,
                         const int* __restrict__ ocnt, float* __restrict__ target) {
    __shared__ unsigned long long keys[NKEY];
    int b = blockIdx.x;
    int n = NSLOT + min(ocnt[b], OCAP);
    for (int i = threadIdx.x; i < n; i += blockDim.x) {
        float v = sval[b * NKEY + i];
        unsigned long long k = 0ull;
        if (v > 0.f) {
            unsigned int ix = (unsigned int)sidx[b * NKEY + i];
            k = ((unsigned long long)__float_as_uint(v) << 32) | (unsigned int)(~ix);
        }
        keys[i] = k;
    }
    __syncthreads();
    int i0 = blockIdx.y * blockDim.x + threadIdx.x;
    if (i0 >= n) return;
    unsigned long long k = keys[i0];
    if (k == 0ull) return;
    int rank = 0;
    for (int j = 0; j < n; ++j) rank += (keys[j] > k) ? 1 : 0;
    if (rank < NCORN) {
        unsigned int ix = ~(unsigned int)(k & 0xffffffffull);
        float v = __uint_as_float((unsigned int)(k >> 32));
        target[(size_t)b * HWP + ix] = v;
    }
}

// 7) second 5x5 NMS on sparse target, output binary mask
__global__ void k_nms2(const float* __restrict__ target, float* __restrict__ M) {
    int i = blockIdx.x * blockDim.x + threadIdx.x;
    if (i >= NPIX) return;
    int b = i / HWP, p = i % HWP, y = p / WW, x = p % WW;
    const float* tb = target + (size_t)b * HWP;
    float t = tb[p];
    float out = 0.f;
    if (t > 0.f) {
        float m = -INFINITY;
        int y0 = max(y - 2, 0), y1 = min(y + 2, HH - 1);
        int x0 = max(x - 2, 0), x1 = min(x + 2, WW - 1);
        for (int yy = y0; yy <= y1; ++yy)
            for (int xx = x0; xx <= x1; ++xx)
                m = fmaxf(m, tb[yy * WW + xx]);
        out = (t == m) ? 1.f : 0.f;
    }
    M[i] = out;
}

// 8a) horizontal 7-tap gaussian (reflect)
__global__ void k_blur7h(const float* __restrict__ M, float* __restrict__ T) {
    int i = blockIdx.x * blockDim.x + threadIdx.x;
    if (i >= NPIX) return;
    int p = i % HWP, x = p % WW;
    const float* row = M + (i - x);
    float acc = 0.f;
#pragma unroll
    for (int t = -3; t <= 3; ++t)
        acc += G7c[t + 3] * row[reflect_idx(x + t, WW)];
    T[i] = acc;
}

// 8b) vertical 7-tap gaussian (reflect)
__global__ void k_blur7v(const float* __restrict__ T, float* __restrict__ corners) {
    int i = blockIdx.x * blockDim.x + threadIdx.x;
    if (i >= NPIX) return;
    int b = i / HWP, p = i % HWP, y = p / WW, x = p % WW;
    const float* cb = T + (size_t)b * HWP;
    float acc = 0.f;
#pragma unroll
    for (int j = -3; j <= 3; ++j)
        acc += G7c[j + 3] * cb[reflect_idx(y + j, HH) * WW + x];
    corners[i] = acc;
}

// 9) fused BCE + laplacian regularizer; per-block partials, NO global atomics
__global__ void k_loss(const float* __restrict__ scores, const float* __restrict__ corners,
                       float* __restrict__ partial) {
    float bce = 0.f, reg = 0.f;
    for (int i = blockIdx.x * blockDim.x + threadIdx.x; i < NPIX;
         i += NB_LOSS * blockDim.x) {
        float p = scores[i];
        float c = corners[i];
        float lp = __logf(p);
        lp = (lp > -100.f) ? lp : -100.f;
        float l1p = __logf(1.f - p);
        l1p = (l1p > -100.f) ? l1p : -100.f;
        bce += -(c * lp + (1.f - c) * l1p);
        int b = i / HWP, pix = i % HWP, y = pix / WW, x = pix % WW;
        const float* sb = scores + (size_t)b * HWP;
        float s25 = 0.f;
        for (int j = -2; j <= 2; ++j) {
            int yy = reflect_idx(y + j, HH);
            const float* r = sb + (size_t)yy * WW;
            for (int ii = -2; ii <= 2; ++ii) {
                int xx = reflect_idx(x + ii, WW);
                s25 += r[xx];
            }
        }
        float lap = (s25 - 25.f * p) * (1.0f / 48.0f);
        reg += p * __expf(-lap);
    }
#pragma unroll
    for (int off = 32; off; off >>= 1) {
        bce += __shfl_down(bce, off);
        reg += __shfl_down(reg, off);
    }
    __shared__ float wb[4], wr[4];
    int wid = threadIdx.x >> 6, lid = threadIdx.x & 63;
    if (lid == 0) { wb[wid] = bce; wr[wid] = reg; }
    __syncthreads();
    if (threadIdx.x == 0) {
        float tb = 0.f, tr = 0.f;
        for (int w = 0; w < 4; ++w) { tb += wb[w]; tr += wr[w]; }
        partial[blockIdx.x] = tb;
        partial[NB_LOSS + blockIdx.x] = tr;
    }
}

// 10) reduce partials -> scalar
__global__ void k_reduce(const float* __restrict__ partial, float* __restrict__ out) {
    float tb = 0.f, tr = 0.f;
    for (int i = threadIdx.x; i < NB_LOSS; i += blockDim.x) {
        tb += partial[i];
        tr += partial[NB_LOSS + i];
    }
#pragma unroll
    for (int off = 32; off; off >>= 1) {
        tb += __shfl_down(tb, off);
        tr += __shfl_down(tr, off);
    }
    __shared__ float wb[4], wr[4];
    int wid = threadIdx.x >> 6, lid = threadIdx.x & 63;
    if (lid == 0) { wb[wid] = tb; wr[wid] = tr; }
    __syncthreads();
    if (threadIdx.x == 0) {
        float sb = 0.f, sr = 0.f;
        for (int w = 0; w < 4; ++w) { sb += wb[w]; sr += wr[w]; }
        float invN = 1.0f / (float)NPIX;
        out[0] = sb * invN + sr * invN * 10.0f;
    }
}

extern "C" void kernel_launch(void* const* d_in, const int* in_sizes, int n_in,
                              void* d_out, int out_size, void* d_ws, size_t ws_size,
                              hipStream_t stream) {
    const float* scores = (const float*)d_in[0];
    const float* imgs   = (const float*)d_in[1];
    float* out = (float*)d_out;

    float* ws = (float*)d_ws;
    float* A0 = ws;                     // gray -> S -> M
    float* A1 = ws + (size_t)NPIX;      // ha -> nms1 rowmax -> blur7 tmp
    float* A2 = ws + 2 * (size_t)NPIX;  // hc -> C -> corners
    float* A3 = ws + 3 * (size_t)NPIX;  // hd -> target
    float* sval = ws + 4 * (size_t)NPIX;          // [BB][NKEY]
    int*   sidx = (int*)(sval + (size_t)BB * NKEY);
    int*   ocnt = (int*)(sidx + (size_t)BB * NKEY);  // [BB]
    float* partial = (float*)(ocnt + BB);            // [2*NB_LOSS]

    const int T = 256;
    const int GB = (NPIX + T - 1) / T;

    k_gray <<<GB, T, 0, stream>>>(imgs, A0);
    k_gradH<<<GB, T, 0, stream>>>(A0, A1, A2, A3);
    k_gfttV<<<GB, T, 0, stream>>>(A1, A2, A3, A0);
    k_nms1h<<<GB, T, 0, stream>>>(A0, A1);
    k_nms1v<<<GB, T, 0, stream>>>(A1, A0, A2);

    hipMemsetAsync(A3, 0, (size_t)NPIX * sizeof(float), stream);       // target
    hipMemsetAsync(ocnt, 0, BB * sizeof(int), stream);

    dim3 gcand(16, 64, BB);
    k_cand<<<gcand, 256, 0, stream>>>(A2, sval, sidx, ocnt);
    dim3 gsel(BB, (NKEY + 511) / 512);
    k_select<<<gsel, 512, 0, stream>>>(sval, sidx, ocnt, A3);
    k_nms2  <<<GB, T, 0, stream>>>(A3, A0);
    k_blur7h<<<GB, T, 0, stream>>>(A0, A1);
    k_blur7v<<<GB, T, 0, stream>>>(A1, A2);
    k_loss  <<<NB_LOSS, T, 0, stream>>>(scores, A2, partial);
    k_reduce<<<1, 256, 0, stream>>>(partial, out);
}